// Round 1
// baseline (325.676 us; speedup 1.0000x reference)
//
#include <hip/hip_runtime.h>
#include <hip/hip_fp16.h>

// SparseSelfAttention: reference == exact softmax attention (mask is a no-op).
// B=4, S=4096, D=256, fp32 in/out. Strategy: fp16 MFMA everywhere.
//  k0: x -> xh+xl (fp16 hi/lo pair, ~22 mantissa bits total)
//  k1: W -> W^T hi/lo fp16
//  k2: 3-term MFMA projection (xh*Wh + xl*Wh + xh*Wl), writes Qf(*log2e), Kf, V^T fp16
//  k3: flash attention, KV tiles 64 keys, double-buffered global_load_lds staging
//      with pre-swizzled source (XOR (row&7)<<4) -> conflict-free ds_read_b128.

typedef _Float16 f16x8 __attribute__((ext_vector_type(8)));
typedef _Float16 f16x4 __attribute__((ext_vector_type(4)));
typedef float    f32x4 __attribute__((ext_vector_type(4)));

#define MFMA16(A, B, C) __builtin_amdgcn_mfma_f32_16x16x32_f16((A), (B), (C), 0, 0, 0)

static __device__ __forceinline__ void gload16(const _Float16* g, _Float16* l) {
    // async global->LDS, 16B per lane; LDS dest must be wave-uniform base + lane*16
    __builtin_amdgcn_global_load_lds(
        (unsigned int __attribute__((address_space(1)))*)g,
        (unsigned int __attribute__((address_space(3)))*)l, 16, 0, 0);
}

// ---------------- kernel 0: convert x to fp16 hi/lo ----------------
__global__ __launch_bounds__(256) void convert_x_kernel(
    const float* __restrict__ x, _Float16* __restrict__ xh, _Float16* __restrict__ xl)
{
    int i = blockIdx.x * 256 + threadIdx.x;  // [0, 1048576) float4s
    float4 v = ((const float4*)x)[i];
    float vv0 = v.x, vv1 = v.y, vv2 = v.z, vv3 = v.w;
    f16x4 h, l;
    _Float16 h0 = (_Float16)vv0; h[0] = h0; l[0] = (_Float16)(vv0 - (float)h0);
    _Float16 h1 = (_Float16)vv1; h[1] = h1; l[1] = (_Float16)(vv1 - (float)h1);
    _Float16 h2 = (_Float16)vv2; h[2] = h2; l[2] = (_Float16)(vv2 - (float)h2);
    _Float16 h3 = (_Float16)vv3; h[3] = h3; l[3] = (_Float16)(vv3 - (float)h3);
    ((f16x4*)xh)[i] = h;
    ((f16x4*)xl)[i] = l;
}

// ---------------- kernel 1: W -> W^T hi/lo fp16 ----------------
__global__ __launch_bounds__(256) void convert_w_kernel(
    const float* __restrict__ Wq, const float* __restrict__ Wk, const float* __restrict__ Wv,
    _Float16* __restrict__ Wth, _Float16* __restrict__ Wtl)
{
    int idx = blockIdx.x * 256 + threadIdx.x;          // [0, 196608)
    int mat = idx >> 16, e = idx & 65535;
    int k = e >> 8, n = e & 255;
    const float* W = (mat == 0) ? Wq : (mat == 1) ? Wk : Wv;
    float v = W[e];
    _Float16 h = (_Float16)v;
    _Float16 lo = (_Float16)(v - (float)h);
    Wth[mat * 65536 + n * 256 + k] = h;   // W^T: [n][k], k contiguous
    Wtl[mat * 65536 + n * 256 + k] = lo;
}

// ---------------- kernel 2: projections ----------------
// grid (256, 3): x=row-tile of 64, y=matrix (0=Q,1=K,2=V). 4 waves x 16 rows.
__global__ __launch_bounds__(256) void proj_kernel(
    const _Float16* __restrict__ xh, const _Float16* __restrict__ xl,
    const _Float16* __restrict__ Wth, const _Float16* __restrict__ Wtl,
    const float* __restrict__ bq, const float* __restrict__ bk, const float* __restrict__ bv,
    _Float16* __restrict__ Qf, _Float16* __restrict__ Kf, _Float16* __restrict__ Vt)
{
    const int mat = blockIdx.y;
    const int tid = threadIdx.x, wid = tid >> 6, lane = tid & 63;
    const int lrow = lane & 15, lgrp = lane >> 4;
    const int row0 = blockIdx.x * 64 + wid * 16;
    const _Float16* Wh = Wth + mat * 65536;
    const _Float16* Wl = Wtl + mat * 65536;
    const float* bias = (mat == 0) ? bq : (mat == 1) ? bk : bv;

    f32x4 acc[16];
#pragma unroll
    for (int i = 0; i < 16; ++i) acc[i] = f32x4{0.f, 0.f, 0.f, 0.f};

#pragma unroll
    for (int ks = 0; ks < 8; ++ks) {
        const int k0 = ks * 32 + lgrp * 8;
        f16x8 Ah = *(const f16x8*)(xh + (size_t)(row0 + lrow) * 256 + k0);
        f16x8 Al = *(const f16x8*)(xl + (size_t)(row0 + lrow) * 256 + k0);
#pragma unroll
        for (int nt = 0; nt < 16; ++nt) {
            const int n = nt * 16 + lrow;
            f16x8 Bh = *(const f16x8*)(Wh + n * 256 + k0);
            f16x8 Bl = *(const f16x8*)(Wl + n * 256 + k0);
            acc[nt] = MFMA16(Ah, Bh, acc[nt]);
            acc[nt] = MFMA16(Al, Bh, acc[nt]);
            acc[nt] = MFMA16(Ah, Bl, acc[nt]);
        }
    }

    const float LOG2E = 1.4426950408889634f;
#pragma unroll
    for (int nt = 0; nt < 16; ++nt) {
        const int n = nt * 16 + lrow;
        const float bb = bias[n];
        if (mat == 2) {
            // V^T layout: [d=256][m=16384], lane's 4 rows are contiguous m
            const int m0 = row0 + lgrp * 4;
            f16x4 vv;
#pragma unroll
            for (int r = 0; r < 4; ++r) vv[r] = (_Float16)(acc[nt][r] + bb);
            *(f16x4*)(Vt + (size_t)n * 16384 + m0) = vv;
        } else {
            _Float16* dst = (mat == 0) ? Qf : Kf;
            const float s = (mat == 0) ? LOG2E : 1.0f;  // fold log2(e) into Q
#pragma unroll
            for (int r = 0; r < 4; ++r) {
                const int grow = row0 + lgrp * 4 + r;
                dst[(size_t)grow * 256 + n] = (_Float16)((acc[nt][r] + bb) * s);
            }
        }
    }
}

// ---------------- kernel 3: flash attention ----------------
// grid (64,4) remapped for XCD locality. Block: 4 waves x 16 q-rows = 64 q.
// KV tile = 64 keys. LDS: K dbuf 64KB + V dbuf 64KB + P 8KB = 136KB.
__global__ __launch_bounds__(256) void attn_kernel(
    const _Float16* __restrict__ Qf, const _Float16* __restrict__ Kf,
    const _Float16* __restrict__ Vt, float* __restrict__ out)
{
    __shared__ _Float16 Kbuf[2][64 * 256];   // [key][d], swizzled 16B slots
    __shared__ _Float16 Vbuf[2][256 * 64];   // [d][key], swizzled 16B slots
    __shared__ _Float16 Pbuf[4][16 * 64];    // per-wave P, swizzled

    const int tid = threadIdx.x, wid = tid >> 6, lane = tid & 63;
    const int lrow = lane & 15, lgrp = lane >> 4;
    // XCD-aware remap: 8 XCDs, give each XCD (pair) mostly one batch
    const int lin = blockIdx.y * 64 + blockIdx.x;
    const int b = (lin & 7) >> 1;
    const int qt = (lin >> 3) + ((lin & 1) << 5);
    const size_t bS = (size_t)b * 4096;
    const size_t qrow0 = bS + (size_t)qt * 64 + wid * 16;

    // Q fragments (16 rows x 256 d) live in registers
    f16x8 Aq[8];
#pragma unroll
    for (int ks = 0; ks < 8; ++ks)
        Aq[ks] = *(const f16x8*)(Qf + (qrow0 + lrow) * 256 + ks * 32 + lgrp * 8);

    f32x4 Oacc[16];
#pragma unroll
    for (int i = 0; i < 16; ++i) Oacc[i] = f32x4{0.f, 0.f, 0.f, 0.f};
    float m_r[4] = {-1e30f, -1e30f, -1e30f, -1e30f};
    float l_r[4] = {0.f, 0.f, 0.f, 0.f};
    _Float16* Pw = Pbuf[wid];

    auto stage = [&](int buf, int t) {
        const size_t krow = bS + (size_t)t * 64;
#pragma unroll
        for (int i = 0; i < 8; ++i) {        // K tile: 2048 x 16B slots
            const int s = i * 256 + tid;
            const int row = s >> 5, c16 = s & 31;
            const int cd = c16 ^ (row & 7);  // pre-swizzled source -> swizzled linear LDS
            gload16(Kf + (krow + row) * 256 + cd * 8, &Kbuf[buf][s * 8]);
        }
#pragma unroll
        for (int i = 0; i < 8; ++i) {        // V^T tile: 2048 x 16B slots
            const int s = i * 256 + tid;
            const int d = s >> 3, c8 = s & 7;
            const int cd = c8 ^ (d & 7);
            gload16(Vt + (size_t)d * 16384 + krow + cd * 8, &Vbuf[buf][s * 8]);
        }
    };

    stage(0, 0);
    asm volatile("s_waitcnt vmcnt(0)" ::: "memory");
    __builtin_amdgcn_s_barrier();

    for (int t = 0; t < 64; ++t) {
        const int cur = t & 1;
        if (t + 1 < 64) stage(cur ^ 1, t + 1);   // prefetch next tile (in flight during compute)
        const _Float16* Kb = Kbuf[cur];
        const _Float16* Vb = Vbuf[cur];

        // ---- scores: 16q x 64k, fp32 accum (already in log2 domain via Q scale) ----
        f32x4 sc[4];
#pragma unroll
        for (int nt = 0; nt < 4; ++nt) sc[nt] = f32x4{0.f, 0.f, 0.f, 0.f};
#pragma unroll
        for (int ks = 0; ks < 8; ++ks) {
#pragma unroll
            for (int nt = 0; nt < 4; ++nt) {
                const int key = nt * 16 + lrow;
                const int c16 = (ks * 4 + lgrp) ^ (key & 7);
                f16x8 Bk = *(const f16x8*)(Kb + key * 256 + c16 * 8);
                sc[nt] = MFMA16(Aq[ks], Bk, sc[nt]);
            }
        }

        // ---- online softmax (per reg r: q = lgrp*4 + r) ----
#pragma unroll
        for (int r = 0; r < 4; ++r) {
            float mx = fmaxf(fmaxf(sc[0][r], sc[1][r]), fmaxf(sc[2][r], sc[3][r]));
#pragma unroll
            for (int off = 8; off > 0; off >>= 1) mx = fmaxf(mx, __shfl_xor(mx, off));
            const float mnew = fmaxf(m_r[r], mx);
            const float scale = exp2f(m_r[r] - mnew);
            m_r[r] = mnew;
            float rs = 0.f;
            const int q = lgrp * 4 + r;
#pragma unroll
            for (int nt = 0; nt < 4; ++nt) {
                const float p = exp2f(sc[nt][r] - mnew);
                rs += p;
                const int key = nt * 16 + lrow;
                const int offb = q * 128 + ((key * 2) ^ ((q & 7) << 4));
                *(_Float16*)((char*)Pw + offb) = (_Float16)p;
            }
#pragma unroll
            for (int off = 8; off > 0; off >>= 1) rs += __shfl_xor(rs, off);
            l_r[r] = l_r[r] * scale + rs;
#pragma unroll
            for (int nt2 = 0; nt2 < 16; ++nt2) Oacc[nt2][r] *= scale;
        }

        // wave-private P: wait LDS writes, then read A-fragments
        asm volatile("s_waitcnt lgkmcnt(0)" ::: "memory");
        f16x8 Ap[2];
#pragma unroll
        for (int ks = 0; ks < 2; ++ks) {
            const int offb = lrow * 128 + ((ks * 64 + lgrp * 16) ^ ((lrow & 7) << 4));
            Ap[ks] = *(const f16x8*)((const char*)Pw + offb);
        }
        // ---- PV: O[16q x 256d] += P * V ----
#pragma unroll
        for (int nt = 0; nt < 16; ++nt) {
            const int d = nt * 16 + lrow;
#pragma unroll
            for (int ks = 0; ks < 2; ++ks) {
                const int c8 = (ks * 4 + lgrp) ^ (d & 7);
                f16x8 Bv = *(const f16x8*)(Vb + d * 64 + c8 * 8);
                Oacc[nt] = MFMA16(Ap[ks], Bv, Oacc[nt]);
            }
        }

        asm volatile("s_waitcnt vmcnt(0)" ::: "memory");  // next tile landed
        __builtin_amdgcn_s_barrier();
    }

    // ---- epilogue: O / l -> fp32 out ----
    float inv[4];
#pragma unroll
    for (int r = 0; r < 4; ++r) inv[r] = 1.0f / l_r[r];
#pragma unroll
    for (int nt = 0; nt < 16; ++nt) {
        const int d = nt * 16 + lrow;
#pragma unroll
        for (int r = 0; r < 4; ++r) {
            const size_t grow = qrow0 + lgrp * 4 + r;
            out[grow * 256 + d] = Oacc[nt][r] * inv[r];
        }
    }
}

extern "C" void kernel_launch(void* const* d_in, const int* in_sizes, int n_in,
                              void* d_out, int out_size, void* d_ws, size_t ws_size,
                              hipStream_t stream) {
    const float* x  = (const float*)d_in[0];
    const float* Wq = (const float*)d_in[1];
    const float* bq = (const float*)d_in[2];
    const float* Wk = (const float*)d_in[3];
    const float* bk = (const float*)d_in[4];
    const float* Wv = (const float*)d_in[5];
    const float* bv = (const float*)d_in[6];
    float* out = (float*)d_out;

    // workspace layout (fp16 elements): needs ~40.8 MB
    _Float16* xh  = (_Float16*)d_ws;
    _Float16* xl  = xh  + 4194304;
    _Float16* Qf  = xl  + 4194304;
    _Float16* Kf  = Qf  + 4194304;
    _Float16* Vt  = Kf  + 4194304;
    _Float16* Wth = Vt  + 4194304;
    _Float16* Wtl = Wth + 196608;

    convert_x_kernel<<<4096, 256, 0, stream>>>(x, xh, xl);
    convert_w_kernel<<<768, 256, 0, stream>>>(Wq, Wk, Wv, Wth, Wtl);
    proj_kernel<<<dim3(256, 3), 256, 0, stream>>>(xh, xl, Wth, Wtl, bq, bk, bv, Qf, Kf, Vt);
    attn_kernel<<<dim3(64, 4), 256, 0, stream>>>(Qf, Kf, Vt, out);
}